// Round 4
// baseline (210.663 us; speedup 1.0000x reference)
//
#include <hip/hip_runtime.h>

// PatchExpand(dim=256) + rearrange + LayerNorm(128), fused, round 4 (= R3 + compile fix).
// x1:[16,4096,256]f32  W:[512,256]f32  gamma,beta:[128]f32 -> out:[16,16384,128]f32
// Barrier-free main loop. W pre-packed bf16 fragment-major in d_ws (256 KiB,
// L2-resident) -> B fragments loaded coalesced from global, no W LDS, no per-chunk
// __syncthreads. A staged once in 16 KiB swizzled LDS. 256-thr blocks, 4 blocks/CU.

typedef __attribute__((ext_vector_type(8))) short bf16x8;
typedef __attribute__((ext_vector_type(4))) float f32x4;
typedef __attribute__((ext_vector_type(8))) unsigned short u16x8;

__device__ __forceinline__ unsigned short f2bf(float f) {
    unsigned u = __builtin_bit_cast(unsigned, f);
    u += 0x7fffu + ((u >> 16) & 1u);   // RNE (inputs finite)
    return (unsigned short)(u >> 16);
}

// ---- prep: W f32[512][256] -> ws bf16, fragment-major ----
// fragment id fid = ((kc*4+wn)*8+ni)*2+ks owns a 1 KiB block: lane l (g=l>>4,c=l&15)
// holds W[wn*128+ni*16+c][kc*64+ks*32+g*8 .. +7] at ws_bytes[fid*1024 + l*16].
__global__ void prep_w(const float* __restrict__ Wg, unsigned short* __restrict__ ws) {
    int sg  = blockIdx.x * 256 + threadIdx.x;   // 0..16383 : one 16B slot each
    int l   = sg & 63;
    int fid = sg >> 6;
    int ks  = fid & 1, ni = (fid >> 1) & 7, wn = (fid >> 4) & 3, kc = fid >> 6;
    int g = l >> 4, c = l & 15;
    int row = wn * 128 + ni * 16 + c;
    int k0  = kc * 64 + ks * 32 + g * 8;
    const f32x4* w4 = reinterpret_cast<const f32x4*>(Wg + (size_t)row * 256 + k0);
    f32x4 v0 = w4[0], v1 = w4[1];
    u16x8 o = { f2bf(v0.x), f2bf(v0.y), f2bf(v0.z), f2bf(v0.w),
                f2bf(v1.x), f2bf(v1.y), f2bf(v1.z), f2bf(v1.w) };
    *reinterpret_cast<u16x8*>(ws + (size_t)sg * 8) = o;
}

// ---- main fused kernel: 256 thr = 4 waves; BM=32 rows, BN=512 (wave wn owns 128) ----
template <bool WS>
__global__ __launch_bounds__(256, 4)
void fused_expand_ln(const float* __restrict__ x1,
                     const float* __restrict__ Wg,
                     const unsigned short* __restrict__ wbf,
                     const float* __restrict__ gamma,
                     const float* __restrict__ beta,
                     float* __restrict__ out) {
    __shared__ unsigned short Alds[32 * 256];   // 16 KiB, XOR-swizzled 16B slots

    const int tid  = threadIdx.x;
    const int l0   = blockIdx.x * 32;
    const int wn   = tid >> 6;                  // 0..3 : LN chunk / p index
    const int lane = tid & 63;
    const int g    = lane >> 4;                 // 0..3
    const int c    = lane & 15;

    // ---- stage all of A once: 32 rows x 256 k, f32 -> bf16, swizzled ----
#pragma unroll
    for (int j = 0; j < 4; ++j) {
        int s   = tid + j * 256;                // slot 0..1023 (16B slots)
        int row = s >> 5, sl = s & 31;
        const f32x4* a4 = reinterpret_cast<const f32x4*>(
            x1 + (size_t)(l0 + row) * 256 + sl * 8);
        f32x4 v0 = __builtin_nontemporal_load(a4);
        f32x4 v1 = __builtin_nontemporal_load(a4 + 1);
        u16x8 o = { f2bf(v0.x), f2bf(v0.y), f2bf(v0.z), f2bf(v0.w),
                    f2bf(v1.x), f2bf(v1.y), f2bf(v1.z), f2bf(v1.w) };
        int sw = (sl & 24) | ((sl & 7) ^ (row & 7));
        *reinterpret_cast<u16x8*>((char*)Alds + row * 512 + sw * 16) = o;
    }
    __syncthreads();                            // the only barrier

    f32x4 acc[2][8];
#pragma unroll
    for (int i = 0; i < 2; ++i)
#pragma unroll
        for (int j = 0; j < 8; ++j) acc[i][j] = (f32x4){0.f, 0.f, 0.f, 0.f};

#pragma unroll 1
    for (int kc = 0; kc < 4; ++kc) {
#pragma unroll
        for (int ks = 0; ks < 2; ++ks) {
            const int sl3 = ks * 4 + g;         // slot low bits within kc
            bf16x8 a[2];
#pragma unroll
            for (int mi = 0; mi < 2; ++mi) {
                int ra = mi * 16 + c;
                a[mi] = *reinterpret_cast<const bf16x8*>(
                    (const char*)Alds + ra * 512 + (kc * 8 | (sl3 ^ (ra & 7))) * 16);
            }
#pragma unroll
            for (int ni = 0; ni < 8; ++ni) {
                bf16x8 b;
                if (WS) {
                    int fid = ((kc * 4 + wn) * 8 + ni) * 2 + ks;
                    b = *reinterpret_cast<const bf16x8*>(
                        wbf + (size_t)fid * 512 + lane * 8);
                } else {
                    int rb = wn * 128 + ni * 16 + c;
                    const f32x4* w4 = reinterpret_cast<const f32x4*>(
                        Wg + (size_t)rb * 256 + kc * 64 + ks * 32 + g * 8);
                    f32x4 v0 = w4[0], v1 = w4[1];
                    u16x8 o = { f2bf(v0.x), f2bf(v0.y), f2bf(v0.z), f2bf(v0.w),
                                f2bf(v1.x), f2bf(v1.y), f2bf(v1.z), f2bf(v1.w) };
                    b = __builtin_bit_cast(bf16x8, o);
                }
                acc[0][ni] = __builtin_amdgcn_mfma_f32_16x16x32_bf16(a[0], b, acc[0][ni], 0, 0, 0);
                acc[1][ni] = __builtin_amdgcn_mfma_f32_16x16x32_bf16(a[1], b, acc[1][ni], 0, 0, 0);
            }
        }
    }

    // ---- fused epilogue: LN over each 128-col chunk, scattered nontemporal write ----
    const int b  = l0 >> 12;
    const int h  = (l0 >> 6) & 63;
    const int w0 = l0 & 63;                     // 0 or 32
    const int p1 = wn >> 1, p2 = wn & 1;

    float gam[8], bet[8];
#pragma unroll
    for (int ni = 0; ni < 8; ++ni) {
        gam[ni] = gamma[ni * 16 + c];
        bet[ni] = beta[ni * 16 + c];
    }

    float* outp = out + (size_t)b * (16384 * 128) + (size_t)(2 * h + p1) * (128 * 128);

#pragma unroll
    for (int mi = 0; mi < 2; ++mi) {
#pragma unroll
        for (int r = 0; r < 4; ++r) {
            float s = 0.f, q = 0.f;
#pragma unroll
            for (int ni = 0; ni < 8; ++ni) {
                float v = acc[mi][ni][r];
                s += v; q += v * v;
            }
#pragma unroll
            for (int m = 1; m < 16; m <<= 1) {
                s += __shfl_xor(s, m, 64);
                q += __shfl_xor(q, m, 64);
            }
            const float mean = s * (1.f / 128.f);
            const float var  = q * (1.f / 128.f) - mean * mean;
            const float rstd = rsqrtf(var + 1e-5f);

            const int w = w0 + mi * 16 + g * 4 + r;
            float* orp = outp + (size_t)(2 * w + p2) * 128;
#pragma unroll
            for (int ni = 0; ni < 8; ++ni) {
                float v = (acc[mi][ni][r] - mean) * rstd;
                __builtin_nontemporal_store(v * gam[ni] + bet[ni], orp + ni * 16 + c);
            }
        }
    }
}

extern "C" void kernel_launch(void* const* d_in, const int* in_sizes, int n_in,
                              void* d_out, int out_size, void* d_ws, size_t ws_size,
                              hipStream_t stream) {
    const float* x1  = (const float*)d_in[0];
    const float* Wg  = (const float*)d_in[1];
    const float* gam = (const float*)d_in[2];
    const float* bet = (const float*)d_in[3];
    float* out       = (float*)d_out;

    if (ws_size >= 262144) {
        unsigned short* wbf = (unsigned short*)d_ws;
        hipLaunchKernelGGL(prep_w, dim3(64), dim3(256), 0, stream, Wg, wbf);
        hipLaunchKernelGGL((fused_expand_ln<true>), dim3(2048), dim3(256), 0, stream,
                           x1, Wg, wbf, gam, bet, out);
    } else {
        hipLaunchKernelGGL((fused_expand_ln<false>), dim3(2048), dim3(256), 0, stream,
                           x1, Wg, nullptr, gam, bet, out);
    }
}